// Round 19
// baseline (78.318 us; speedup 1.0000x reference)
//
#include <hip/hip_runtime.h>
#include <hip/hip_bf16.h>
#include <stdint.h>

// Problem: B=16, S=1024, IN=1024, OUT=1024.
// Reference collapses: softmax row-sums are exactly 1 (key mask always has >=1
// live column), so out = leaky_relu(xs @ (Wlin@Wv)^T + (Wlin@bv + blin)).
//
// Round 19: main moved to the m97 regime (128x128, BK=32, 4 waves, 256 thr)
// with the ONLY empirically-clean LDS pattern (bf16 row-pair + swz128; fp32
// tiles conflicted despite analysis, rounds 16/17) and double-buffered
// counted-vmcnt(4) staging. 32KB LDS + launch_bounds(256,4) -> 4 blocks/CU
// (the cross-block TLP that m97 showed is worth ~100+ TF over 2 blocks/CU).
// prepA/prepB unchanged (conversion split across both prep dispatches).

#define M_TOT 16384   // B*S
#define KDIM  1024
#define NDIM  1024
#define NKT   32      // K-tiles of BK=32

typedef __attribute__((ext_vector_type(8))) short bf16x8;
typedef __attribute__((ext_vector_type(4))) float f32x4;
typedef __attribute__((ext_vector_type(4))) unsigned short u16x4;
typedef __attribute__((ext_vector_type(8))) unsigned short u16x8;

static __device__ __forceinline__ unsigned short f2bf(float f) {
    union { float f; unsigned int u; } v; v.f = f;
    unsigned int u = v.u;
    return (unsigned short)((u + 0x7fffu + ((u >> 16) & 1u)) >> 16);  // RNE
}

static __device__ __forceinline__ u16x8 pack8(float4 a, float4 b) {
    u16x8 p = { f2bf(a.x), f2bf(a.y), f2bf(a.z), f2bf(a.w),
                f2bf(b.x), f2bf(b.y), f2bf(b.z), f2bf(b.w) };
    return p;
}

static __device__ __forceinline__ void gload16(const void* g, void* l) {
    __builtin_amdgcn_global_load_lds(
        (__attribute__((address_space(1))) void*)(g),
        (__attribute__((address_space(3))) void*)(l), 16, 0, 0);
}

// Involutive byte-swizzle for 128B-line LDS regions: XOR line bits (7-9) into
// 16B-slot bits (4-6). With bf16 row-pair packing: measured 0 conflicts.
static __device__ __forceinline__ int swz128(int p) {
    return p ^ (((p >> 7) & 7) << 4);
}

// Half-of-xs converter: 1024 blocks x 256 thr x 8 elems x 4 iters = 8.4M elems.
static __device__ __forceinline__ void convert_half(
    const float* __restrict__ xs, unsigned short* __restrict__ Xb,
    int cb, int t, size_t half_base) {
    const size_t base = half_base + (((size_t)cb) * 256 + t) * 8;
    #pragma unroll
    for (int itr = 0; itr < 4; ++itr) {
        const size_t idx = base + (size_t)itr * (size_t)(1024 * 256 * 8);
        float4 a = *(const float4*)&xs[idx];
        float4 b = *(const float4*)&xs[idx + 4];
        *(u16x8*)&Xb[idx] = pack8(a, b);
    }
}

// ---------------------------------------------------------------------------
// prepA: [0,256) transpose Wv[d][i] -> Wvt[i][d] bf16 (64x64 tiles, padded
//        fp32 LDS); [256,512) Wlin -> Wlb bf16; [512,768) bias fold;
//        [768,1792) convert first half of xs.
// ---------------------------------------------------------------------------
__global__ __launch_bounds__(256) void prepA_kernel(
    const float* __restrict__ Wv, const float* __restrict__ Wlin,
    const float* __restrict__ bv, const float* __restrict__ blin,
    const float* __restrict__ xs, unsigned short* __restrict__ Wvt,
    unsigned short* __restrict__ Wlb, float* __restrict__ bcomb,
    unsigned short* __restrict__ Xb) {
    __shared__ float Tl[64 * 65];
    const int bid = blockIdx.x;
    const int t = threadIdx.x;

    if (bid >= 768) {
        convert_half(xs, Xb, bid - 768, t, 0);
        return;
    }

    if (bid < 256) {
        const int dt = bid >> 4;
        const int it = bid & 15;
        const int r = t >> 2;
        const int c0 = (t & 3) * 16;
        #pragma unroll
        for (int u = 0; u < 4; ++u) {
            float4 v = *(const float4*)&Wv[((size_t)(dt * 64 + r)) * NDIM + it * 64 + c0 + 4 * u];
            Tl[r * 65 + c0 + 4 * u + 0] = v.x;
            Tl[r * 65 + c0 + 4 * u + 1] = v.y;
            Tl[r * 65 + c0 + 4 * u + 2] = v.z;
            Tl[r * 65 + c0 + 4 * u + 3] = v.w;
        }
        __syncthreads();
        const int i = t >> 2;
        const int dq = (t & 3) * 16;
        float v[16];
        #pragma unroll
        for (int u = 0; u < 16; ++u) v[u] = Tl[(dq + u) * 65 + i];
        u16x8 p0 = { f2bf(v[0]), f2bf(v[1]), f2bf(v[2]), f2bf(v[3]),
                     f2bf(v[4]), f2bf(v[5]), f2bf(v[6]), f2bf(v[7]) };
        u16x8 p1 = { f2bf(v[8]), f2bf(v[9]), f2bf(v[10]), f2bf(v[11]),
                     f2bf(v[12]), f2bf(v[13]), f2bf(v[14]), f2bf(v[15]) };
        unsigned short* dst = &Wvt[((size_t)(it * 64 + i)) * KDIM + dt * 64 + dq];
        *(u16x8*)dst = p0;
        *(u16x8*)(dst + 8) = p1;
    } else if (bid < 512) {
        const size_t idx = (((size_t)(bid - 256)) * 256 + t) * 16;
        float4 a = *(const float4*)&Wlin[idx];
        float4 b = *(const float4*)&Wlin[idx + 4];
        float4 c = *(const float4*)&Wlin[idx + 8];
        float4 d = *(const float4*)&Wlin[idx + 12];
        *(u16x8*)&Wlb[idx] = pack8(a, b);
        *(u16x8*)&Wlb[idx + 8] = pack8(c, d);
    } else {
        const int wave = t >> 6, lane = t & 63;
        const int o = (bid - 512) * 4 + wave;
        float s = 0.f;
        for (int d = lane; d < KDIM; d += 64) s += Wlin[o * KDIM + d] * bv[d];
        #pragma unroll
        for (int off = 32; off > 0; off >>= 1) s += __shfl_down(s, off, 64);
        if (lane == 0) bcomb[o] = s + blin[o];
    }
}

// ---------------------------------------------------------------------------
// prepB: [0,256): Wc[o][i] = sum_d Wlb[o][d]*Wvt[i][d] (64x64 tiles, bf16,
//        both operands gload_lds); [256,1280): convert second half of xs.
// ---------------------------------------------------------------------------
__global__ __launch_bounds__(256) void prepB_kernel(
    const unsigned short* __restrict__ Wlb, const unsigned short* __restrict__ Wvt,
    const float* __restrict__ xs, unsigned short* __restrict__ Wc,
    unsigned short* __restrict__ Xb) {
    __shared__ unsigned short As[64 * 32];
    __shared__ unsigned short Bs[64 * 32];
    const int bid = blockIdx.x;
    const int t = threadIdx.x;

    if (bid >= 256) {
        convert_half(xs, Xb, bid - 256, t, (size_t)8388608);
        return;
    }

    const int ot = bid >> 4;
    const int it = bid & 15;
    const int w = t >> 6, l = t & 63;
    const int wr = (w >> 1) * 32, wc = (w & 1) * 32;
    const int lr = l & 15, lk = l >> 4;

    f32x4 acc[2][2] = {};

    const unsigned short* gA = &Wlb[((size_t)(ot * 64 + (t >> 2))) * KDIM + (t & 3) * 8];
    const unsigned short* gB = &Wvt[((size_t)(it * 64 + (t >> 2))) * KDIM + (t & 3) * 8];
    unsigned short* lA = &As[w * 512];
    unsigned short* lB = &Bs[w * 512];

    for (int kt = 0; kt < KDIM / 32; ++kt) {
        gload16(gA + kt * 32, lA);
        gload16(gB + kt * 32, lB);
        __syncthreads();
        bf16x8 af[2], bfr[2];
        #pragma unroll
        for (int fi = 0; fi < 2; ++fi)
            af[fi] = *(bf16x8*)&As[(wr + fi * 16 + lr) * 32 + lk * 8];
        #pragma unroll
        for (int fj = 0; fj < 2; ++fj)
            bfr[fj] = *(bf16x8*)&Bs[(wc + fj * 16 + lr) * 32 + lk * 8];
        #pragma unroll
        for (int fi = 0; fi < 2; ++fi)
            #pragma unroll
            for (int fj = 0; fj < 2; ++fj)
                acc[fi][fj] = __builtin_amdgcn_mfma_f32_16x16x32_bf16(
                    af[fi], bfr[fj], acc[fi][fj], 0, 0, 0);
        __syncthreads();
    }
    #pragma unroll
    for (int fi = 0; fi < 2; ++fi)
        #pragma unroll
        for (int fj = 0; fj < 2; ++fj)
            #pragma unroll
            for (int r = 0; r < 4; ++r) {
                const int o = ot * 64 + wr + fi * 16 + lk * 4 + r;
                const int i = it * 64 + wc + fj * 16 + lr;
                Wc[(size_t)o * KDIM + i] = f2bf(acc[fi][fj][r]);
            }
}

// ---------------------------------------------------------------------------
// main_m97: out = leaky(Xb @ Wc^T + bcomb). m97 regime + proven swizzle.
// BM=BN=128, BK=32, 4 waves (2x2 of 64x64), 256 thr, per-wave acc[4][4].
// LDS 32768 = 2 slots x (A 8KB + B 8KB), bf16 row-pair + swz128 (0-conflict).
// Stage T+1 (4 gloads/thread: 2 A-chunks + 2 B-chunks) at tile top; counted
// vmcnt(4); barrier; frag reads; 16 MFMA (setprio); end barrier.
// Grid 1024 = 4 blocks/CU (launch_bounds(256,4)); bijective XCD swizzle.
// ---------------------------------------------------------------------------
__global__ __launch_bounds__(256, 4) void main_m97(
    const unsigned short* __restrict__ Xb, const unsigned short* __restrict__ Wc,
    const float* __restrict__ bcomb, float* __restrict__ out) {
    extern __shared__ char lds[];  // 32768
    const int tid = threadIdx.x;
    const int w = tid >> 6, l = tid & 63;
    const int wm = w >> 1, wn = w & 1;
    const int lr = l & 15, lk = l >> 4;

    // XCD swizzle (1024 % 8 == 0, bijective): 128 consecutive per XCD
    // -> blocks sharing an mt panel land on one XCD (A-panel L2 reuse).
    const int swzb = ((blockIdx.x & 7) << 7) | (blockIdx.x >> 3);
    const int mt = swzb >> 3, nt = swzb & 7;

    // reader byte offsets: row r, k-slot lk -> logical byte
    // P = (r>>1)*128 + (r&1)*64 + lk*16; physical = swz128(P). (proven)
    int aoff[4], boff[4];
    #pragma unroll
    for (int fi = 0; fi < 4; ++fi) {
        const int r = wm * 64 + fi * 16 + lr;
        aoff[fi] = swz128(((r >> 1) << 7) | ((r & 1) << 6) | (lk << 4));
    }
    #pragma unroll
    for (int fj = 0; fj < 4; ++fj) {
        const int r = wn * 64 + fj * 16 + lr;
        boff[fj] = 8192 + swz128(((r >> 1) << 7) | ((r & 1) << 6) | (lk << 4));
    }

    // staging: linear LDS dests, pre-swizzled global sources (rule #21).
    // A region 8KB = 2 chunks of 4KB; q = c*4096 + tid*16.
    const char* srcA[2];
    const char* srcB[2];
    #pragma unroll
    for (int c = 0; c < 2; ++c) {
        const int q = c * 4096 + tid * 16;
        const int p = swz128(q);
        const int r = ((p >> 7) << 1) | ((p >> 6) & 1);   // 0..127
        srcA[c] = (const char*)Xb + ((size_t)(mt * 128 + r)) * 2048 + (p & 63);
        srcB[c] = (const char*)Wc + ((size_t)(nt * 128 + r)) * 2048 + (p & 63);
    }
    const int ldsw = w * 1024;   // wave-uniform base within each 4KB chunk

    f32x4 acc[4][4] = {};

#define STAGE(TT, SLOT)                                                        \
    do {                                                                       \
        gload16(srcA[0] + (size_t)(TT) * 64, lds + (SLOT) + 0 * 4096 + ldsw);  \
        gload16(srcA[1] + (size_t)(TT) * 64, lds + (SLOT) + 1 * 4096 + ldsw);  \
        gload16(srcB[0] + (size_t)(TT) * 64, lds + (SLOT) + 8192 + ldsw);      \
        gload16(srcB[1] + (size_t)(TT) * 64, lds + (SLOT) + 12288 + ldsw);     \
    } while (0)

    // prologue: stage tile 0 into slot 0
    STAGE(0, 0);

    for (int kt = 0; kt < NKT; ++kt) {
        const int cur = (kt & 1) << 14;
        const int nxt = (cur ^ 16384);

        if (kt < NKT - 1) {
            STAGE(kt + 1, nxt);
            asm volatile("s_waitcnt vmcnt(4)" ::: "memory");  // tile kt landed
        } else {
            asm volatile("s_waitcnt vmcnt(0)" ::: "memory");
        }
        __builtin_amdgcn_s_barrier();

        const char* cbuf = lds + cur;
        bf16x8 af[4], bfr[4];
        #pragma unroll
        for (int fi = 0; fi < 4; ++fi)
            af[fi] = *(const bf16x8*)(cbuf + aoff[fi]);
        #pragma unroll
        for (int fj = 0; fj < 4; ++fj)
            bfr[fj] = *(const bf16x8*)(cbuf + boff[fj]);

        __builtin_amdgcn_s_setprio(1);
        #pragma unroll
        for (int fi = 0; fi < 4; ++fi)
            #pragma unroll
            for (int fj = 0; fj < 4; ++fj)
                acc[fi][fj] = __builtin_amdgcn_mfma_f32_16x16x32_bf16(
                    af[fi], bfr[fj], acc[fi][fj], 0, 0, 0);
        __builtin_amdgcn_s_setprio(0);

        // end barrier: tile-kt ds_reads retired (compiler lgkm-waits before
        // MFMA) before next iter's STAGE overwrites cur.
        __builtin_amdgcn_s_barrier();
    }
#undef STAGE

    // epilogue: + bias, leaky_relu, fp32 store
    #pragma unroll
    for (int fi = 0; fi < 4; ++fi)
        #pragma unroll
        for (int fj = 0; fj < 4; ++fj) {
            const int col = nt * 128 + wn * 64 + fj * 16 + lr;
            const float b = bcomb[col];
            #pragma unroll
            for (int r = 0; r < 4; ++r) {
                const int row = mt * 128 + wm * 64 + fi * 16 + lk * 4 + r;
                float v = acc[fi][fj][r] + b;
                out[(size_t)row * NDIM + col] = v >= 0.f ? v : 0.01f * v;
            }
        }
}

// ---------------------------------------------------------------------------
// Fallback main GEMM (fused fp32->bf16 A path, 128x128) if ws is too small.
// ---------------------------------------------------------------------------
__global__ __launch_bounds__(256) void main_gemm_f32(
    const float* __restrict__ X, const unsigned short* __restrict__ Wc,
    const float* __restrict__ bcomb, float* __restrict__ out) {
    __shared__ unsigned short As[128 * 32];
    __shared__ unsigned short Bs[128 * 32];
    const int t = threadIdx.x;
    const int nt = blockIdx.x & 7;
    const int mt = blockIdx.x >> 3;
    const int w = t >> 6, l = t & 63;
    const int wr = (w >> 1) * 64, wcc = (w & 1) * 64;
    const int lr = l & 15, lk = l >> 4;

    f32x4 acc[4][4] = {};

    const int arow = t >> 3;
    const int akq = t & 7;
    const int brow = t >> 2;
    const int bc4 = t & 3;

    for (int kt = 0; kt < KDIM / 32; ++kt) {
        float4 av[4];
        #pragma unroll
        for (int j = 0; j < 4; ++j) {
            const int row = j * 32 + arow;
            av[j] = *(const float4*)&X[(mt * 128 + row) * KDIM + kt * 32 + akq * 4];
        }
        __syncthreads();
        #pragma unroll
        for (int j = 0; j < 4; ++j) {
            const int row = j * 32 + arow;
            u16x4 p = { f2bf(av[j].x), f2bf(av[j].y), f2bf(av[j].z), f2bf(av[j].w) };
            *(u16x4*)&As[row * 32 + akq * 4] = p;
        }
        #pragma unroll
        for (int j = 0; j < 2; ++j) {
            const int row = j * 64 + brow;
            const unsigned short* g = &Wc[(nt * 128 + row) * KDIM + kt * 32 + bc4 * 8];
            unsigned short* ldst = &Bs[(j * 256 + w * 64) * 8];
            gload16(g, ldst);
        }
        __syncthreads();
        bf16x8 af[4], bfr[4];
        #pragma unroll
        for (int fi = 0; fi < 4; ++fi)
            af[fi] = *(bf16x8*)&As[(wr + fi * 16 + lr) * 32 + lk * 8];
        #pragma unroll
        for (int fj = 0; fj < 4; ++fj)
            bfr[fj] = *(bf16x8*)&Bs[(wcc + fj * 16 + lr) * 32 + lk * 8];
        #pragma unroll
        for (int fi = 0; fi < 4; ++fi)
            #pragma unroll
            for (int fj = 0; fj < 4; ++fj)
                acc[fi][fj] = __builtin_amdgcn_mfma_f32_16x16x32_bf16(
                    af[fi], bfr[fj], acc[fi][fj], 0, 0, 0);
    }

    #pragma unroll
    for (int fi = 0; fi < 4; ++fi)
        #pragma unroll
        for (int fj = 0; fj < 4; ++fj) {
            const int col = nt * 128 + wcc + fj * 16 + lr;
            const float b = bcomb[col];
            #pragma unroll
            for (int r = 0; r < 4; ++r) {
                const int row = mt * 128 + wr + fi * 16 + lk * 4 + r;
                float v = acc[fi][fj][r] + b;
                out[row * NDIM + col] = v >= 0.f ? v : 0.01f * v;
            }
        }
}

extern "C" void kernel_launch(void* const* d_in, const int* in_sizes, int n_in,
                              void* d_out, int out_size, void* d_ws, size_t ws_size,
                              hipStream_t stream) {
    const float* xs   = (const float*)d_in[0];
    // d_in[1] mask unused: softmax row-sums are exactly 1.
    const float* Wv   = (const float*)d_in[6];
    const float* bv   = (const float*)d_in[7];
    const float* Wlin = (const float*)d_in[8];
    const float* blin = (const float*)d_in[9];

    unsigned short* Wc = (unsigned short*)d_ws;                         // 2 MB
    float* bcomb = (float*)((char*)d_ws + 2097152);                     // 4 KB
    unsigned short* Xb = (unsigned short*)((char*)d_ws + 2101248);      // 32 MB
    float* out = (float*)d_out;

    // transient scratch in d_out (64 MB, fully overwritten by the final GEMM)
    unsigned short* Wvt = (unsigned short*)d_out;                       // 2 MB
    unsigned short* Wlb = (unsigned short*)((char*)d_out + 2097152);    // 2 MB

    const size_t NEED = 2101248 + (size_t)M_TOT * KDIM * 2;
    if (ws_size >= NEED) {
        (void)hipFuncSetAttribute((const void*)main_m97,
                                  hipFuncAttributeMaxDynamicSharedMemorySize,
                                  32768);
        hipLaunchKernelGGL(prepA_kernel, dim3(768 + 1024), dim3(256), 0, stream,
                           Wv, Wlin, bv, blin, xs, Wvt, Wlb, bcomb, Xb);
        hipLaunchKernelGGL(prepB_kernel, dim3(256 + 1024), dim3(256), 0, stream,
                           Wlb, Wvt, xs, Wc, Xb);
        hipLaunchKernelGGL(main_m97, dim3(1024), dim3(256), 32768, stream,
                           Xb, Wc, bcomb, out);
    } else {
        hipLaunchKernelGGL(prepA_kernel, dim3(768), dim3(256), 0, stream,
                           Wv, Wlin, bv, blin, xs, Wvt, Wlb, bcomb, Xb);
        hipLaunchKernelGGL(prepB_kernel, dim3(256), dim3(256), 0, stream,
                           Wlb, Wvt, xs, Wc, Xb);
        hipLaunchKernelGGL(main_gemm_f32, dim3((M_TOT / 128) * (NDIM / 128)),
                           dim3(256), 0, stream, xs, Wc, bcomb, out);
    }
}

// Round 20
// 72.698 us; speedup vs baseline: 1.0773x; 1.0773x over previous
//
#include <hip/hip_runtime.h>
#include <hip/hip_bf16.h>
#include <stdint.h>

// Problem: B=16, S=1024, IN=1024, OUT=1024.
// Reference collapses: softmax row-sums are exactly 1 (key mask always has >=1
// live column), so out = leaky_relu(xs @ (Wlin@Wv)^T + (Wlin@bv + blin)).
//
// Round 20: conversion-free pipeline (r16 showed it ties the best total even
// with a broken main) + reg-staged fused A on the PROVEN main_mb skeleton.
// Why this fusion attempt differs from the 7 failures: launch_bounds(512,4)
// gives a 128-VGPR budget >= the ~110 needed (r13's budget was 84 -> compiler
// sank the A-loads, VGPR=68 signature); 2 blocks/CU cross-hide barriers
// (r5-8/r12 were 1/CU); full-tile prefetch distance; linear-dest ds_writes
// (guaranteed 0-conflict) with inverse-swizzled global source (r13 mapping);
// reads use the empirically-only-clean bf16 row-pair + swz128 pattern.

#define M_TOT 16384   // B*S
#define KDIM  1024
#define NDIM  1024
#define NKT   32      // K-tiles of BK=32

typedef __attribute__((ext_vector_type(8))) short bf16x8;
typedef __attribute__((ext_vector_type(4))) float f32x4;
typedef __attribute__((ext_vector_type(4))) unsigned short u16x4;
typedef __attribute__((ext_vector_type(8))) unsigned short u16x8;

static __device__ __forceinline__ unsigned short f2bf(float f) {
    union { float f; unsigned int u; } v; v.f = f;
    unsigned int u = v.u;
    return (unsigned short)((u + 0x7fffu + ((u >> 16) & 1u)) >> 16);  // RNE
}

static __device__ __forceinline__ u16x8 pack8(float4 a, float4 b) {
    u16x8 p = { f2bf(a.x), f2bf(a.y), f2bf(a.z), f2bf(a.w),
                f2bf(b.x), f2bf(b.y), f2bf(b.z), f2bf(b.w) };
    return p;
}

static __device__ __forceinline__ void gload16(const void* g, void* l) {
    __builtin_amdgcn_global_load_lds(
        (__attribute__((address_space(1))) void*)(g),
        (__attribute__((address_space(3))) void*)(l), 16, 0, 0);
}

// Involutive byte-swizzle for 128B-line LDS regions: XOR line bits (7-9) into
// 16B-slot bits (4-6). With bf16 row-pair packing: measured 0 conflicts.
static __device__ __forceinline__ int swz128(int p) {
    return p ^ (((p >> 7) & 7) << 4);
}

// ---------------------------------------------------------------------------
// prep0: [0,256) transpose Wv[d][i] -> Wvt[i][d] bf16 (64x64 tiles, padded
//        fp32 LDS); [256,512) Wlin -> Wlb bf16; [512,768) bias fold.
// ---------------------------------------------------------------------------
__global__ __launch_bounds__(256) void prep0_kernel(
    const float* __restrict__ Wv, const float* __restrict__ Wlin,
    const float* __restrict__ bv, const float* __restrict__ blin,
    unsigned short* __restrict__ Wvt, unsigned short* __restrict__ Wlb,
    float* __restrict__ bcomb) {
    __shared__ float Tl[64 * 65];
    const int bid = blockIdx.x;
    const int t = threadIdx.x;

    if (bid < 256) {
        const int dt = bid >> 4;
        const int it = bid & 15;
        const int r = t >> 2;
        const int c0 = (t & 3) * 16;
        #pragma unroll
        for (int u = 0; u < 4; ++u) {
            float4 v = *(const float4*)&Wv[((size_t)(dt * 64 + r)) * NDIM + it * 64 + c0 + 4 * u];
            Tl[r * 65 + c0 + 4 * u + 0] = v.x;
            Tl[r * 65 + c0 + 4 * u + 1] = v.y;
            Tl[r * 65 + c0 + 4 * u + 2] = v.z;
            Tl[r * 65 + c0 + 4 * u + 3] = v.w;
        }
        __syncthreads();
        const int i = t >> 2;
        const int dq = (t & 3) * 16;
        float v[16];
        #pragma unroll
        for (int u = 0; u < 16; ++u) v[u] = Tl[(dq + u) * 65 + i];
        u16x8 p0 = { f2bf(v[0]), f2bf(v[1]), f2bf(v[2]), f2bf(v[3]),
                     f2bf(v[4]), f2bf(v[5]), f2bf(v[6]), f2bf(v[7]) };
        u16x8 p1 = { f2bf(v[8]), f2bf(v[9]), f2bf(v[10]), f2bf(v[11]),
                     f2bf(v[12]), f2bf(v[13]), f2bf(v[14]), f2bf(v[15]) };
        unsigned short* dst = &Wvt[((size_t)(it * 64 + i)) * KDIM + dt * 64 + dq];
        *(u16x8*)dst = p0;
        *(u16x8*)(dst + 8) = p1;
    } else if (bid < 512) {
        const size_t idx = (((size_t)(bid - 256)) * 256 + t) * 16;
        float4 a = *(const float4*)&Wlin[idx];
        float4 b = *(const float4*)&Wlin[idx + 4];
        float4 c = *(const float4*)&Wlin[idx + 8];
        float4 d = *(const float4*)&Wlin[idx + 12];
        *(u16x8*)&Wlb[idx] = pack8(a, b);
        *(u16x8*)&Wlb[idx + 8] = pack8(c, d);
    } else {
        const int wave = t >> 6, lane = t & 63;
        const int o = (bid - 512) * 4 + wave;
        float s = 0.f;
        for (int d = lane; d < KDIM; d += 64) s += Wlin[o * KDIM + d] * bv[d];
        #pragma unroll
        for (int off = 32; off > 0; off >>= 1) s += __shfl_down(s, off, 64);
        if (lane == 0) bcomb[o] = s + blin[o];
    }
}

// ---------------------------------------------------------------------------
// wcomb: Wc[o][i] = sum_d Wlb[o][d] * Wvt[i][d]. 64x64 tiles, 256 blocks,
// 4 waves (2x2 of 32x32), both operands via global_load_lds.
// ---------------------------------------------------------------------------
__global__ __launch_bounds__(256) void wcomb_kernel(
    const unsigned short* __restrict__ Wlb, const unsigned short* __restrict__ Wvt,
    unsigned short* __restrict__ Wc) {
    __shared__ unsigned short As[64 * 32];
    __shared__ unsigned short Bs[64 * 32];
    const int t = threadIdx.x;
    const int ot = blockIdx.x >> 4;
    const int it = blockIdx.x & 15;
    const int w = t >> 6, l = t & 63;
    const int wr = (w >> 1) * 32, wc = (w & 1) * 32;
    const int lr = l & 15, lk = l >> 4;

    f32x4 acc[2][2] = {};

    const unsigned short* gA = &Wlb[((size_t)(ot * 64 + (t >> 2))) * KDIM + (t & 3) * 8];
    const unsigned short* gB = &Wvt[((size_t)(it * 64 + (t >> 2))) * KDIM + (t & 3) * 8];
    unsigned short* lA = &As[w * 512];
    unsigned short* lB = &Bs[w * 512];

    for (int kt = 0; kt < KDIM / 32; ++kt) {
        gload16(gA + kt * 32, lA);
        gload16(gB + kt * 32, lB);
        __syncthreads();
        bf16x8 af[2], bfr[2];
        #pragma unroll
        for (int fi = 0; fi < 2; ++fi)
            af[fi] = *(bf16x8*)&As[(wr + fi * 16 + lr) * 32 + lk * 8];
        #pragma unroll
        for (int fj = 0; fj < 2; ++fj)
            bfr[fj] = *(bf16x8*)&Bs[(wc + fj * 16 + lr) * 32 + lk * 8];
        #pragma unroll
        for (int fi = 0; fi < 2; ++fi)
            #pragma unroll
            for (int fj = 0; fj < 2; ++fj)
                acc[fi][fj] = __builtin_amdgcn_mfma_f32_16x16x32_bf16(
                    af[fi], bfr[fj], acc[fi][fj], 0, 0, 0);
        __syncthreads();
    }
    #pragma unroll
    for (int fi = 0; fi < 2; ++fi)
        #pragma unroll
        for (int fj = 0; fj < 2; ++fj)
            #pragma unroll
            for (int r = 0; r < 4; ++r) {
                const int o = ot * 64 + wr + fi * 16 + lk * 4 + r;
                const int i = it * 64 + wc + fj * 16 + lr;
                Wc[(size_t)o * KDIM + i] = f2bf(acc[fi][fj][r]);
            }
}

// ---------------------------------------------------------------------------
// main_fused2: out = leaky(bf16(xs) @ Wc^T + bcomb), A converted in-kernel.
// main_mb skeleton (proven 44.3us): BM=256, BN=128, BK=32, 8 waves (4Mx2N),
// per-wave 64x64 = acc[4][4]. LDS 49152 = 2 bufs x (A 16KB + B 8KB), bf16
// row-pair + swz128 reads (0-conflict).
// A path: per tile, 4 float4 fp32 loads for T+1 issued at tile TOP (full-tile
// latency cover), cvt + 2 LINEAR ds_write_b128 (t*16: 0-conflict) after the
// MFMAs; content inverse-swizzled via pre-swizzled global source (rule #21).
// B path: 1 gload_lds/thread for T+1 at tile top. Counted vmcnt(5) at top.
// launch_bounds(512,4): VGPR budget 128 >= ~110 needed -> no load-sinking
// (r13's failure signature was budget 84 -> VGPR 68). Grid 512 = 2/CU.
// ---------------------------------------------------------------------------
__global__ __launch_bounds__(512, 4) void main_fused2(
    const float* __restrict__ xs, const unsigned short* __restrict__ Wc,
    const float* __restrict__ bcomb, float* __restrict__ out) {
    extern __shared__ char lds[];  // 49152
    const int tid = threadIdx.x;
    const int w = tid >> 6, l = tid & 63;
    const int wm = w >> 1, wn = w & 1;
    const int lr = l & 15, lk = l >> 4;

    // XCD swizzle (512 % 8 == 0, bijective): 64 consecutive per XCD.
    const int swzb = ((blockIdx.x & 7) << 6) | (blockIdx.x >> 3);
    const int mt = swzb >> 3, nt = swzb & 7;

    // reader byte offsets (proven row-pair + swz128)
    int aoff[4], boff[4];
    #pragma unroll
    for (int fi = 0; fi < 4; ++fi) {
        const int r = wm * 64 + fi * 16 + lr;
        aoff[fi] = swz128(((r >> 1) << 7) | ((r & 1) << 6) | (lk << 4));
    }
    #pragma unroll
    for (int fj = 0; fj < 4; ++fj) {
        const int r = wn * 64 + fj * 16 + lr;
        boff[fj] = 16384 + swz128(((r >> 1) << 7) | ((r & 1) << 6) | (lk << 4));
    }

    // A staging: thread fills linear bytes q = c*8192 + tid*16 (c in {0,1});
    // content = logical byte p = swz128(q) of the [256][32]bf16 row-pair tile:
    // row = (p>>7)*2 + ((p>>6)&1), bf16-col-byte = p&63 -> fp32 col = (p&63)/2.
    const float* srcA32[2];
    #pragma unroll
    for (int c = 0; c < 2; ++c) {
        const int q = c * 8192 + tid * 16;
        const int p = swz128(q);
        const int r = ((p >> 7) << 1) | ((p >> 6) & 1);   // 0..255
        srcA32[c] = xs + ((size_t)(mt * 256 + r)) * KDIM + ((p & 63) >> 1);
    }
    const int ldsA0 = tid * 16;          // linear dest, chunk 0
    const int ldsA1 = 8192 + tid * 16;   // chunk 1

    // B staging: pre-swizzled global source, linear gload_lds dest.
    const char* srcB;
    {
        const int q = tid * 16;
        const int p = swz128(q);
        const int r = ((p >> 7) << 1) | ((p >> 6) & 1);   // 0..127
        srcB = (const char*)Wc + ((size_t)(nt * 128 + r)) * 2048 + (p & 63);
    }
    const int ldsBw = 16384 + w * 1024;

    f32x4 acc[4][4] = {};
    float4 avA[4];

#define LOAD_A(TT)                                                             \
    do {                                                                       \
        avA[0] = *(const float4*)(srcA32[0] + (TT) * 32);                      \
        avA[1] = *(const float4*)(srcA32[0] + (TT) * 32 + 4);                  \
        avA[2] = *(const float4*)(srcA32[1] + (TT) * 32);                      \
        avA[3] = *(const float4*)(srcA32[1] + (TT) * 32 + 4);                  \
    } while (0)

#define CVT_A(BUF)                                                             \
    do {                                                                       \
        *(u16x8*)((BUF) + ldsA0) = pack8(avA[0], avA[1]);                      \
        *(u16x8*)((BUF) + ldsA1) = pack8(avA[2], avA[3]);                      \
    } while (0)

    // prologue: A(0) -> regs -> cvt into buf0; B(0) gload into buf0.
    LOAD_A(0);
    gload16(srcB, lds + ldsBw);
    CVT_A(lds);                                   // waits A(0) regs only
    asm volatile("s_waitcnt vmcnt(0)" ::: "memory");   // B(0) landed
    asm volatile("s_waitcnt lgkmcnt(0)" ::: "memory");
    __builtin_amdgcn_s_barrier();

    for (int kt = 0; kt < NKT; ++kt) {
        char* cbuf = lds + (kt & 1) * 24576;
        char* nbuf = lds + ((kt & 1) ^ 1) * 24576;

        // issue next tile's loads FIRST (full-tile latency cover)
        if (kt < NKT - 1) {
            LOAD_A(kt + 1);
            gload16(srcB + (size_t)(kt + 1) * 64, nbuf + ldsBw);
        }

        // compute tile kt
        bf16x8 af[4], bfr[4];
        #pragma unroll
        for (int fi = 0; fi < 4; ++fi)
            af[fi] = *(const bf16x8*)(cbuf + aoff[fi]);
        #pragma unroll
        for (int fj = 0; fj < 4; ++fj)
            bfr[fj] = *(const bf16x8*)(cbuf + boff[fj]);

        __builtin_amdgcn_s_setprio(1);
        #pragma unroll
        for (int fi = 0; fi < 4; ++fi)
            #pragma unroll
            for (int fj = 0; fj < 4; ++fj)
                acc[fi][fj] = __builtin_amdgcn_mfma_f32_16x16x32_bf16(
                    af[fi], bfr[fj], acc[fi][fj], 0, 0, 0);
        __builtin_amdgcn_s_setprio(0);

        // cvt A(kt+1) into nbuf (compiler waits only the 4 A-loads; B(kt+1)
        // gload stays in flight -> counted discipline preserved)
        if (kt < NKT - 1) {
            CVT_A(nbuf);
            // drain ds ops (frag reads + our 2 writes) before the barrier;
            // B(kt+1) remains the only outstanding VMEM.
            asm volatile("s_waitcnt lgkmcnt(0)" ::: "memory");
            __builtin_amdgcn_s_barrier();
            // top of next tile: B(kt+1) landed (issued a full tile ago)
            asm volatile("s_waitcnt vmcnt(0)" ::: "memory");
            __builtin_amdgcn_s_barrier();
        }
    }

    // epilogue: + bias, leaky_relu, fp32 store
    #pragma unroll
    for (int fi = 0; fi < 4; ++fi)
        #pragma unroll
        for (int fj = 0; fj < 4; ++fj) {
            const int col = nt * 128 + wn * 64 + fj * 16 + lr;
            const float b = bcomb[col];
            #pragma unroll
            for (int r = 0; r < 4; ++r) {
                const int row = mt * 256 + wm * 64 + fi * 16 + lk * 4 + r;
                float v = acc[fi][fj][r] + b;
                out[(size_t)row * NDIM + col] = v >= 0.f ? v : 0.01f * v;
            }
        }
#undef CVT_A
#undef LOAD_A
}

// ---------------------------------------------------------------------------
// Fallback main GEMM (fused fp32->bf16 A path, 128x128) if ws is too small.
// ---------------------------------------------------------------------------
__global__ __launch_bounds__(256) void main_gemm_f32(
    const float* __restrict__ X, const unsigned short* __restrict__ Wc,
    const float* __restrict__ bcomb, float* __restrict__ out) {
    __shared__ unsigned short As[128 * 32];
    __shared__ unsigned short Bs[128 * 32];
    const int t = threadIdx.x;
    const int nt = blockIdx.x & 7;
    const int mt = blockIdx.x >> 3;
    const int w = t >> 6, l = t & 63;
    const int wr = (w >> 1) * 64, wcc = (w & 1) * 64;
    const int lr = l & 15, lk = l >> 4;

    f32x4 acc[4][4] = {};

    const int arow = t >> 3;
    const int akq = t & 7;
    const int brow = t >> 2;
    const int bc4 = t & 3;

    for (int kt = 0; kt < KDIM / 32; ++kt) {
        float4 av[4];
        #pragma unroll
        for (int j = 0; j < 4; ++j) {
            const int row = j * 32 + arow;
            av[j] = *(const float4*)&X[(mt * 128 + row) * KDIM + kt * 32 + akq * 4];
        }
        __syncthreads();
        #pragma unroll
        for (int j = 0; j < 4; ++j) {
            const int row = j * 32 + arow;
            u16x4 p = { f2bf(av[j].x), f2bf(av[j].y), f2bf(av[j].z), f2bf(av[j].w) };
            *(u16x4*)&As[row * 32 + akq * 4] = p;
        }
        #pragma unroll
        for (int j = 0; j < 2; ++j) {
            const int row = j * 64 + brow;
            const unsigned short* g = &Wc[(nt * 128 + row) * KDIM + kt * 32 + bc4 * 8];
            unsigned short* ldst = &Bs[(j * 256 + w * 64) * 8];
            gload16(g, ldst);
        }
        __syncthreads();
        bf16x8 af[4], bfr[4];
        #pragma unroll
        for (int fi = 0; fi < 4; ++fi)
            af[fi] = *(bf16x8*)&As[(wr + fi * 16 + lr) * 32 + lk * 8];
        #pragma unroll
        for (int fj = 0; fj < 4; ++fj)
            bfr[fj] = *(bf16x8*)&Bs[(wcc + fj * 16 + lr) * 32 + lk * 8];
        #pragma unroll
        for (int fi = 0; fi < 4; ++fi)
            #pragma unroll
            for (int fj = 0; fj < 4; ++fj)
                acc[fi][fj] = __builtin_amdgcn_mfma_f32_16x16x32_bf16(
                    af[fi], bfr[fj], acc[fi][fj], 0, 0, 0);
    }

    #pragma unroll
    for (int fi = 0; fi < 4; ++fi)
        #pragma unroll
        for (int fj = 0; fj < 4; ++fj) {
            const int col = nt * 128 + wcc + fj * 16 + lr;
            const float b = bcomb[col];
            #pragma unroll
            for (int r = 0; r < 4; ++r) {
                const int row = mt * 128 + wr + fi * 16 + lk * 4 + r;
                float v = acc[fi][fj][r] + b;
                out[row * NDIM + col] = v >= 0.f ? v : 0.01f * v;
            }
        }
}

extern "C" void kernel_launch(void* const* d_in, const int* in_sizes, int n_in,
                              void* d_out, int out_size, void* d_ws, size_t ws_size,
                              hipStream_t stream) {
    const float* xs   = (const float*)d_in[0];
    // d_in[1] mask unused: softmax row-sums are exactly 1.
    const float* Wv   = (const float*)d_in[6];
    const float* bv   = (const float*)d_in[7];
    const float* Wlin = (const float*)d_in[8];
    const float* blin = (const float*)d_in[9];

    unsigned short* Wc = (unsigned short*)d_ws;                         // 2 MB
    float* bcomb = (float*)((char*)d_ws + 2097152);                     // 4 KB
    float* out = (float*)d_out;

    // transient scratch in d_out (64 MB, fully overwritten by the final GEMM)
    unsigned short* Wvt = (unsigned short*)d_out;                       // 2 MB
    unsigned short* Wlb = (unsigned short*)((char*)d_out + 2097152);    // 2 MB

    const size_t NEED = 2101248;
    hipLaunchKernelGGL(prep0_kernel, dim3(768), dim3(256), 0, stream,
                       Wv, Wlin, bv, blin, Wvt, Wlb, bcomb);
    hipLaunchKernelGGL(wcomb_kernel, dim3(256), dim3(256), 0, stream,
                       Wlb, Wvt, Wc);
    if (ws_size >= NEED) {
        (void)hipFuncSetAttribute((const void*)main_fused2,
                                  hipFuncAttributeMaxDynamicSharedMemorySize,
                                  49152);
        hipLaunchKernelGGL(main_fused2, dim3(512), dim3(512), 49152, stream,
                           xs, Wc, bcomb, out);
    } else {
        hipLaunchKernelGGL(main_gemm_f32, dim3((M_TOT / 128) * (NDIM / 128)),
                           dim3(256), 0, stream, xs, Wc, bcomb, out);
    }
}

// Round 21
// 72.610 us; speedup vs baseline: 1.0786x; 1.0012x over previous
//
#include <hip/hip_runtime.h>
#include <hip/hip_bf16.h>
#include <stdint.h>

// Problem: B=16, S=1024, IN=1024, OUT=1024.
// Reference collapses: softmax row-sums are exactly 1 (key mask always has >=1
// live column), so out = leaky_relu(xs @ (Wlin@Wv)^T + (Wlin@bv + blin)).
//
// Round 21: fix r20's load-sinking (VGPR=60 signature: compiler sank the A
// prefetch loads to just before CVT_A despite the 128-reg budget). Fix = a
// zero-cost `asm volatile("" ::: "memory")` pin after {loads, frag reads}:
// global loads cannot be sunk past a may-write-memory asm, so they ISSUE at
// tile top; the avA waitcnt still lands at CVT_A. Also: single barrier per
// tile (each wave's lgkm(0)+vmcnt(0) before the barrier retires its frag
// reads, CVT writes, and B-gload -> one sync point suffices).

#define M_TOT 16384   // B*S
#define KDIM  1024
#define NDIM  1024
#define NKT   32      // K-tiles of BK=32

typedef __attribute__((ext_vector_type(8))) short bf16x8;
typedef __attribute__((ext_vector_type(4))) float f32x4;
typedef __attribute__((ext_vector_type(4))) unsigned short u16x4;
typedef __attribute__((ext_vector_type(8))) unsigned short u16x8;

static __device__ __forceinline__ unsigned short f2bf(float f) {
    union { float f; unsigned int u; } v; v.f = f;
    unsigned int u = v.u;
    return (unsigned short)((u + 0x7fffu + ((u >> 16) & 1u)) >> 16);  // RNE
}

static __device__ __forceinline__ u16x8 pack8(float4 a, float4 b) {
    u16x8 p = { f2bf(a.x), f2bf(a.y), f2bf(a.z), f2bf(a.w),
                f2bf(b.x), f2bf(b.y), f2bf(b.z), f2bf(b.w) };
    return p;
}

static __device__ __forceinline__ void gload16(const void* g, void* l) {
    __builtin_amdgcn_global_load_lds(
        (__attribute__((address_space(1))) void*)(g),
        (__attribute__((address_space(3))) void*)(l), 16, 0, 0);
}

// Involutive byte-swizzle for 128B-line LDS regions: XOR line bits (7-9) into
// 16B-slot bits (4-6). With bf16 row-pair packing: measured 0 conflicts.
static __device__ __forceinline__ int swz128(int p) {
    return p ^ (((p >> 7) & 7) << 4);
}

// ---------------------------------------------------------------------------
// prep0: [0,256) transpose Wv[d][i] -> Wvt[i][d] bf16 (64x64 tiles, padded
//        fp32 LDS); [256,512) Wlin -> Wlb bf16; [512,768) bias fold.
// ---------------------------------------------------------------------------
__global__ __launch_bounds__(256) void prep0_kernel(
    const float* __restrict__ Wv, const float* __restrict__ Wlin,
    const float* __restrict__ bv, const float* __restrict__ blin,
    unsigned short* __restrict__ Wvt, unsigned short* __restrict__ Wlb,
    float* __restrict__ bcomb) {
    __shared__ float Tl[64 * 65];
    const int bid = blockIdx.x;
    const int t = threadIdx.x;

    if (bid < 256) {
        const int dt = bid >> 4;
        const int it = bid & 15;
        const int r = t >> 2;
        const int c0 = (t & 3) * 16;
        #pragma unroll
        for (int u = 0; u < 4; ++u) {
            float4 v = *(const float4*)&Wv[((size_t)(dt * 64 + r)) * NDIM + it * 64 + c0 + 4 * u];
            Tl[r * 65 + c0 + 4 * u + 0] = v.x;
            Tl[r * 65 + c0 + 4 * u + 1] = v.y;
            Tl[r * 65 + c0 + 4 * u + 2] = v.z;
            Tl[r * 65 + c0 + 4 * u + 3] = v.w;
        }
        __syncthreads();
        const int i = t >> 2;
        const int dq = (t & 3) * 16;
        float v[16];
        #pragma unroll
        for (int u = 0; u < 16; ++u) v[u] = Tl[(dq + u) * 65 + i];
        u16x8 p0 = { f2bf(v[0]), f2bf(v[1]), f2bf(v[2]), f2bf(v[3]),
                     f2bf(v[4]), f2bf(v[5]), f2bf(v[6]), f2bf(v[7]) };
        u16x8 p1 = { f2bf(v[8]), f2bf(v[9]), f2bf(v[10]), f2bf(v[11]),
                     f2bf(v[12]), f2bf(v[13]), f2bf(v[14]), f2bf(v[15]) };
        unsigned short* dst = &Wvt[((size_t)(it * 64 + i)) * KDIM + dt * 64 + dq];
        *(u16x8*)dst = p0;
        *(u16x8*)(dst + 8) = p1;
    } else if (bid < 512) {
        const size_t idx = (((size_t)(bid - 256)) * 256 + t) * 16;
        float4 a = *(const float4*)&Wlin[idx];
        float4 b = *(const float4*)&Wlin[idx + 4];
        float4 c = *(const float4*)&Wlin[idx + 8];
        float4 d = *(const float4*)&Wlin[idx + 12];
        *(u16x8*)&Wlb[idx] = pack8(a, b);
        *(u16x8*)&Wlb[idx + 8] = pack8(c, d);
    } else {
        const int wave = t >> 6, lane = t & 63;
        const int o = (bid - 512) * 4 + wave;
        float s = 0.f;
        for (int d = lane; d < KDIM; d += 64) s += Wlin[o * KDIM + d] * bv[d];
        #pragma unroll
        for (int off = 32; off > 0; off >>= 1) s += __shfl_down(s, off, 64);
        if (lane == 0) bcomb[o] = s + blin[o];
    }
}

// ---------------------------------------------------------------------------
// wcomb: Wc[o][i] = sum_d Wlb[o][d] * Wvt[i][d]. 64x64 tiles, 256 blocks,
// 4 waves (2x2 of 32x32), both operands via global_load_lds.
// ---------------------------------------------------------------------------
__global__ __launch_bounds__(256) void wcomb_kernel(
    const unsigned short* __restrict__ Wlb, const unsigned short* __restrict__ Wvt,
    unsigned short* __restrict__ Wc) {
    __shared__ unsigned short As[64 * 32];
    __shared__ unsigned short Bs[64 * 32];
    const int t = threadIdx.x;
    const int ot = blockIdx.x >> 4;
    const int it = blockIdx.x & 15;
    const int w = t >> 6, l = t & 63;
    const int wr = (w >> 1) * 32, wc = (w & 1) * 32;
    const int lr = l & 15, lk = l >> 4;

    f32x4 acc[2][2] = {};

    const unsigned short* gA = &Wlb[((size_t)(ot * 64 + (t >> 2))) * KDIM + (t & 3) * 8];
    const unsigned short* gB = &Wvt[((size_t)(it * 64 + (t >> 2))) * KDIM + (t & 3) * 8];
    unsigned short* lA = &As[w * 512];
    unsigned short* lB = &Bs[w * 512];

    for (int kt = 0; kt < KDIM / 32; ++kt) {
        gload16(gA + kt * 32, lA);
        gload16(gB + kt * 32, lB);
        __syncthreads();
        bf16x8 af[2], bfr[2];
        #pragma unroll
        for (int fi = 0; fi < 2; ++fi)
            af[fi] = *(bf16x8*)&As[(wr + fi * 16 + lr) * 32 + lk * 8];
        #pragma unroll
        for (int fj = 0; fj < 2; ++fj)
            bfr[fj] = *(bf16x8*)&Bs[(wc + fj * 16 + lr) * 32 + lk * 8];
        #pragma unroll
        for (int fi = 0; fi < 2; ++fi)
            #pragma unroll
            for (int fj = 0; fj < 2; ++fj)
                acc[fi][fj] = __builtin_amdgcn_mfma_f32_16x16x32_bf16(
                    af[fi], bfr[fj], acc[fi][fj], 0, 0, 0);
        __syncthreads();
    }
    #pragma unroll
    for (int fi = 0; fi < 2; ++fi)
        #pragma unroll
        for (int fj = 0; fj < 2; ++fj)
            #pragma unroll
            for (int r = 0; r < 4; ++r) {
                const int o = ot * 64 + wr + fi * 16 + lk * 4 + r;
                const int i = it * 64 + wc + fj * 16 + lr;
                Wc[(size_t)o * KDIM + i] = f2bf(acc[fi][fj][r]);
            }
}

// ---------------------------------------------------------------------------
// main_fused3: out = leaky(bf16(xs) @ Wc^T + bcomb), A converted in-kernel.
// main_mb skeleton: BM=256, BN=128, BK=32, 8 waves (4Mx2N), per-wave 64x64 =
// acc[4][4]. LDS 49152 = 2 bufs x (A 16KB + B 8KB), row-pair swz128 reads.
// Per tile: {LOAD_A(T+1) + gload_B(T+1) + frag reads; MEMORY PIN; 16 MFMA
// (setprio); CVT_A(T+1) -> nbuf (linear dests); vmcnt(0)+lgkm(0); ONE
// barrier}. Pin prevents load-sinking (r20's VGPR=60 failure). Grid 512 =
// 2 blocks/CU, launch_bounds(512,4), bijective XCD swizzle.
// ---------------------------------------------------------------------------
__global__ __launch_bounds__(512, 4) void main_fused3(
    const float* __restrict__ xs, const unsigned short* __restrict__ Wc,
    const float* __restrict__ bcomb, float* __restrict__ out) {
    extern __shared__ char lds[];  // 49152
    const int tid = threadIdx.x;
    const int w = tid >> 6, l = tid & 63;
    const int wm = w >> 1, wn = w & 1;
    const int lr = l & 15, lk = l >> 4;

    // XCD swizzle (512 % 8 == 0, bijective): 64 consecutive per XCD.
    const int swzb = ((blockIdx.x & 7) << 6) | (blockIdx.x >> 3);
    const int mt = swzb >> 3, nt = swzb & 7;

    // reader byte offsets (proven row-pair + swz128)
    int aoff[4], boff[4];
    #pragma unroll
    for (int fi = 0; fi < 4; ++fi) {
        const int r = wm * 64 + fi * 16 + lr;
        aoff[fi] = swz128(((r >> 1) << 7) | ((r & 1) << 6) | (lk << 4));
    }
    #pragma unroll
    for (int fj = 0; fj < 4; ++fj) {
        const int r = wn * 64 + fj * 16 + lr;
        boff[fj] = 16384 + swz128(((r >> 1) << 7) | ((r & 1) << 6) | (lk << 4));
    }

    // A staging: thread fills linear bytes q = c*8192 + tid*16 (c in {0,1});
    // content = logical byte p = swz128(q) of the [256][32]bf16 row-pair tile.
    const float* srcA32[2];
    #pragma unroll
    for (int c = 0; c < 2; ++c) {
        const int q = c * 8192 + tid * 16;
        const int p = swz128(q);
        const int r = ((p >> 7) << 1) | ((p >> 6) & 1);   // 0..255
        srcA32[c] = xs + ((size_t)(mt * 256 + r)) * KDIM + ((p & 63) >> 1);
    }
    const int ldsA0 = tid * 16;
    const int ldsA1 = 8192 + tid * 16;

    // B staging: pre-swizzled global source, linear gload_lds dest.
    const char* srcB;
    {
        const int q = tid * 16;
        const int p = swz128(q);
        const int r = ((p >> 7) << 1) | ((p >> 6) & 1);   // 0..127
        srcB = (const char*)Wc + ((size_t)(nt * 128 + r)) * 2048 + (p & 63);
    }
    const int ldsBw = 16384 + w * 1024;

    f32x4 acc[4][4] = {};
    float4 avA[4];

#define LOAD_A(TT)                                                             \
    do {                                                                       \
        avA[0] = *(const float4*)(srcA32[0] + (TT) * 32);                      \
        avA[1] = *(const float4*)(srcA32[0] + (TT) * 32 + 4);                  \
        avA[2] = *(const float4*)(srcA32[1] + (TT) * 32);                      \
        avA[3] = *(const float4*)(srcA32[1] + (TT) * 32 + 4);                  \
    } while (0)

#define CVT_A(BUF)                                                             \
    do {                                                                       \
        *(u16x8*)((BUF) + ldsA0) = pack8(avA[0], avA[1]);                      \
        *(u16x8*)((BUF) + ldsA1) = pack8(avA[2], avA[3]);                      \
    } while (0)

    // prologue: A(0)->regs->cvt into buf0; B(0) gload into buf0.
    LOAD_A(0);
    gload16(srcB, lds + ldsBw);
    CVT_A(lds);                                        // waits A(0) regs only
    asm volatile("s_waitcnt vmcnt(0) lgkmcnt(0)" ::: "memory");
    __builtin_amdgcn_s_barrier();

    for (int kt = 0; kt < NKT; ++kt) {
        char* cbuf = lds + (kt & 1) * 24576;
        char* nbuf = lds + ((kt & 1) ^ 1) * 24576;

        // issue next tile's loads FIRST
        if (kt < NKT - 1) {
            LOAD_A(kt + 1);
            gload16(srcB + (size_t)(kt + 1) * 64, nbuf + ldsBw);
        }

        // frag reads for tile kt
        bf16x8 af[4], bfr[4];
        #pragma unroll
        for (int fi = 0; fi < 4; ++fi)
            af[fi] = *(const bf16x8*)(cbuf + aoff[fi]);
        #pragma unroll
        for (int fj = 0; fj < 4; ++fj)
            bfr[fj] = *(const bf16x8*)(cbuf + boff[fj]);

        // MEMORY PIN: a may-write-memory asm -- the global loads above cannot
        // be sunk below this point (they must ISSUE here); no waitcnt forced.
        asm volatile("" ::: "memory");

        __builtin_amdgcn_s_setprio(1);
        #pragma unroll
        for (int fi = 0; fi < 4; ++fi)
            #pragma unroll
            for (int fj = 0; fj < 4; ++fj)
                acc[fi][fj] = __builtin_amdgcn_mfma_f32_16x16x32_bf16(
                    af[fi], bfr[fj], acc[fi][fj], 0, 0, 0);
        __builtin_amdgcn_s_setprio(0);

        if (kt < NKT - 1) {
            // cvt A(kt+1) into nbuf (hw waits the 4 A-loads here)
            CVT_A(nbuf);
            // retire this wave's frag reads + cvt writes + B-gload, then ONE
            // barrier: after it, buf[kt+1] is complete and buf[kt] is free.
            asm volatile("s_waitcnt vmcnt(0) lgkmcnt(0)" ::: "memory");
            __builtin_amdgcn_s_barrier();
        }
    }

    // epilogue: + bias, leaky_relu, fp32 store
    #pragma unroll
    for (int fi = 0; fi < 4; ++fi)
        #pragma unroll
        for (int fj = 0; fj < 4; ++fj) {
            const int col = nt * 128 + wn * 64 + fj * 16 + lr;
            const float b = bcomb[col];
            #pragma unroll
            for (int r = 0; r < 4; ++r) {
                const int row = mt * 256 + wm * 64 + fi * 16 + lk * 4 + r;
                float v = acc[fi][fj][r] + b;
                out[(size_t)row * NDIM + col] = v >= 0.f ? v : 0.01f * v;
            }
        }
#undef CVT_A
#undef LOAD_A
}

// ---------------------------------------------------------------------------
// Fallback main GEMM (fused fp32->bf16 A path, 128x128) if ws is too small.
// ---------------------------------------------------------------------------
__global__ __launch_bounds__(256) void main_gemm_f32(
    const float* __restrict__ X, const unsigned short* __restrict__ Wc,
    const float* __restrict__ bcomb, float* __restrict__ out) {
    __shared__ unsigned short As[128 * 32];
    __shared__ unsigned short Bs[128 * 32];
    const int t = threadIdx.x;
    const int nt = blockIdx.x & 7;
    const int mt = blockIdx.x >> 3;
    const int w = t >> 6, l = t & 63;
    const int wr = (w >> 1) * 64, wcc = (w & 1) * 64;
    const int lr = l & 15, lk = l >> 4;

    f32x4 acc[4][4] = {};

    const int arow = t >> 3;
    const int akq = t & 7;
    const int brow = t >> 2;
    const int bc4 = t & 3;

    for (int kt = 0; kt < KDIM / 32; ++kt) {
        float4 av[4];
        #pragma unroll
        for (int j = 0; j < 4; ++j) {
            const int row = j * 32 + arow;
            av[j] = *(const float4*)&X[(mt * 128 + row) * KDIM + kt * 32 + akq * 4];
        }
        __syncthreads();
        #pragma unroll
        for (int j = 0; j < 4; ++j) {
            const int row = j * 32 + arow;
            u16x4 p = { f2bf(av[j].x), f2bf(av[j].y), f2bf(av[j].z), f2bf(av[j].w) };
            *(u16x4*)&As[row * 32 + akq * 4] = p;
        }
        #pragma unroll
        for (int j = 0; j < 2; ++j) {
            const int row = j * 64 + brow;
            const unsigned short* g = &Wc[(nt * 128 + row) * KDIM + kt * 32 + bc4 * 8];
            unsigned short* ldst = &Bs[(j * 256 + w * 64) * 8];
            gload16(g, ldst);
        }
        __syncthreads();
        bf16x8 af[4], bfr[4];
        #pragma unroll
        for (int fi = 0; fi < 4; ++fi)
            af[fi] = *(bf16x8*)&As[(wr + fi * 16 + lr) * 32 + lk * 8];
        #pragma unroll
        for (int fj = 0; fj < 4; ++fj)
            bfr[fj] = *(bf16x8*)&Bs[(wcc + fj * 16 + lr) * 32 + lk * 8];
        #pragma unroll
        for (int fi = 0; fi < 4; ++fi)
            #pragma unroll
            for (int fj = 0; fj < 4; ++fj)
                acc[fi][fj] = __builtin_amdgcn_mfma_f32_16x16x32_bf16(
                    af[fi], bfr[fj], acc[fi][fj], 0, 0, 0);
    }

    #pragma unroll
    for (int fi = 0; fi < 4; ++fi)
        #pragma unroll
        for (int fj = 0; fj < 4; ++fj) {
            const int col = nt * 128 + wcc + fj * 16 + lr;
            const float b = bcomb[col];
            #pragma unroll
            for (int r = 0; r < 4; ++r) {
                const int row = mt * 128 + wr + fi * 16 + lk * 4 + r;
                float v = acc[fi][fj][r] + b;
                out[row * NDIM + col] = v >= 0.f ? v : 0.01f * v;
            }
        }
}

extern "C" void kernel_launch(void* const* d_in, const int* in_sizes, int n_in,
                              void* d_out, int out_size, void* d_ws, size_t ws_size,
                              hipStream_t stream) {
    const float* xs   = (const float*)d_in[0];
    // d_in[1] mask unused: softmax row-sums are exactly 1.
    const float* Wv   = (const float*)d_in[6];
    const float* bv   = (const float*)d_in[7];
    const float* Wlin = (const float*)d_in[8];
    const float* blin = (const float*)d_in[9];

    unsigned short* Wc = (unsigned short*)d_ws;                         // 2 MB
    float* bcomb = (float*)((char*)d_ws + 2097152);                     // 4 KB
    float* out = (float*)d_out;

    // transient scratch in d_out (64 MB, fully overwritten by the final GEMM)
    unsigned short* Wvt = (unsigned short*)d_out;                       // 2 MB
    unsigned short* Wlb = (unsigned short*)((char*)d_out + 2097152);    // 2 MB

    const size_t NEED = 2101248;
    hipLaunchKernelGGL(prep0_kernel, dim3(768), dim3(256), 0, stream,
                       Wv, Wlin, bv, blin, Wvt, Wlb, bcomb);
    hipLaunchKernelGGL(wcomb_kernel, dim3(256), dim3(256), 0, stream,
                       Wlb, Wvt, Wc);
    if (ws_size >= NEED) {
        (void)hipFuncSetAttribute((const void*)main_fused3,
                                  hipFuncAttributeMaxDynamicSharedMemorySize,
                                  49152);
        hipLaunchKernelGGL(main_fused3, dim3(512), dim3(512), 49152, stream,
                           xs, Wc, bcomb, out);
    } else {
        hipLaunchKernelGGL(main_gemm_f32, dim3((M_TOT / 128) * (NDIM / 128)),
                           dim3(256), 0, stream, xs, Wc, bcomb, out);
    }
}